// Round 8
// baseline (230.287 us; speedup 1.0000x reference)
//
#include <hip/hip_runtime.h>

#define EPSV 1e-5f

__device__ __forceinline__ float block_reduce_sum(float v, float* lds) {
  #pragma unroll
  for (int off = 32; off > 0; off >>= 1) v += __shfl_down(v, off, 64);
  int lane = threadIdx.x & 63;
  int wid  = threadIdx.x >> 6;
  __syncthreads();
  if (lane == 0) lds[wid] = v;
  __syncthreads();
  float r = 0.f;
  if (threadIdx.x == 0) {
    int nw = blockDim.x >> 6;
    for (int i = 0; i < nw; ++i) r += lds[i];
  }
  return r;
}

// Stage x[b] (3x32x32) into zero-padded LDS [3][34][34].
__device__ __forceinline__ void stage_x(const float* __restrict__ x, float* xt, int b, int tid) {
  {
    float4* t4 = (float4*)xt;
    #pragma unroll
    for (int i = 0; i < 4; ++i) {
      int idx = i * 256 + tid;
      if (idx < 867) t4[idx] = make_float4(0.f, 0.f, 0.f, 0.f);
    }
  }
  __syncthreads();
  {
    const float4* x4 = (const float4*)(x + b * 3072);
    #pragma unroll
    for (int k = 0; k < 3; ++k) {
      int e4 = k * 256 + tid;
      float4 v = x4[e4];
      int w0 = e4 * 4;
      int ch = w0 >> 10;
      int pos = w0 & 1023;
      int r = pos >> 5, c = pos & 31;
      int base = ch * 1156 + (r + 1) * 34 + (c + 1);
      xt[base] = v.x; xt[base + 1] = v.y; xt[base + 2] = v.z; xt[base + 3] = v.w;
    }
  }
  __syncthreads();
}

// K1 v3: conv1 + stats partials; grid (1024, 2): blockIdx.y picks 8 of 16 co.
__global__ __launch_bounds__(256) void k1_conv1_stats(
    const float* __restrict__ x, const float* __restrict__ w1, const float* __restrict__ b1,
    float* __restrict__ partials /* [16][2][1024] */) {
  __shared__ float xt[3468];
  __shared__ float red[64];
  const int tid = threadIdx.x, b = blockIdx.x;
  const int co0 = blockIdx.y * 8;
  stage_x(x, xt, b, tid);

  const int c = tid & 31, r0 = (tid >> 5) * 4;
  const int sbase = r0 * 34 + c;
  float xv[54];  // 3 ci x 6 rows x 3 cols
  #pragma unroll
  for (int ci = 0; ci < 3; ++ci)
    #pragma unroll
    for (int dr = 0; dr < 6; ++dr)
      #pragma unroll
      for (int dx = 0; dx < 3; ++dx)
        xv[ci * 18 + dr * 3 + dx] = xt[ci * 1156 + sbase + dr * 34 + dx];

  const int lane = tid & 63, wid = tid >> 6;
  #pragma unroll
  for (int cl = 0; cl < 8; ++cl) {
    const int co = co0 + cl;
    float a0, a1, a2, a3;
    a0 = a1 = a2 = a3 = b1[co];
    #pragma unroll
    for (int ci = 0; ci < 3; ++ci)
      #pragma unroll
      for (int ky = 0; ky < 3; ++ky)
        #pragma unroll
        for (int kx = 0; kx < 3; ++kx) {
          float w = w1[co * 27 + ci * 9 + ky * 3 + kx];
          a0 = fmaf(xv[ci * 18 + (0 + ky) * 3 + kx], w, a0);
          a1 = fmaf(xv[ci * 18 + (1 + ky) * 3 + kx], w, a1);
          a2 = fmaf(xv[ci * 18 + (2 + ky) * 3 + kx], w, a2);
          a3 = fmaf(xv[ci * 18 + (3 + ky) * 3 + kx], w, a3);
        }
    float s = a0 + a1 + a2 + a3;
    float q = fmaf(a0, a0, fmaf(a1, a1, fmaf(a2, a2, a3 * a3)));
    #pragma unroll
    for (int o = 32; o > 0; o >>= 1) {
      s += __shfl_down(s, o, 64);
      q += __shfl_down(q, o, 64);
    }
    if (lane == 0) { red[wid * 16 + cl * 2] = s; red[wid * 16 + cl * 2 + 1] = q; }
  }
  __syncthreads();
  if (tid < 16) {
    int cl = tid >> 1, sel = tid & 1;
    float r = red[cl * 2 + sel] + red[16 + cl * 2 + sel] +
              red[32 + cl * 2 + sel] + red[48 + cl * 2 + sel];
    partials[((co0 + cl) * 2 + sel) * 1024 + b] = r;
  }
}

// K2/K6: reduce partials -> scale/shift per channel.
__global__ __launch_bounds__(256) void k_bn_finalize(
    const float* __restrict__ partials, int nb, float invN,
    const float* __restrict__ gamma, const float* __restrict__ beta,
    float* __restrict__ stats, int C) {
  __shared__ float lds[4];
  int c = blockIdx.x;
  float s = 0.f, q = 0.f;
  for (int i = threadIdx.x; i < nb; i += blockDim.x) {
    s += partials[(c * 2 + 0) * nb + i];
    q += partials[(c * 2 + 1) * nb + i];
  }
  s = block_reduce_sum(s, lds);
  q = block_reduce_sum(q, lds);
  if (threadIdx.x == 0) {
    float mean = s * invN;
    float var  = q * invN - mean * mean;
    float scale = gamma[c] * rsqrtf(var + EPSV);
    stats[c]     = scale;
    stats[C + c] = beta[c] - mean * scale;
  }
}

// K3 v3: conv1 + BN + ReLU + basis_pool -> h1; grid (1024, 2): 8 of 16 channels.
__global__ __launch_bounds__(256) void k3_pool1(
    const float* __restrict__ x, const float* __restrict__ w1, const float* __restrict__ b1,
    const float* __restrict__ stats1, const float* __restrict__ pw, const float* __restrict__ pb,
    float* __restrict__ h1) {
  __shared__ float xt[3468];
  const int tid = threadIdx.x, b = blockIdx.x;
  const int c0 = blockIdx.y * 8;
  stage_x(x, xt, b, tid);

  const int ow = tid & 15, oh = tid >> 4;
  const int wbase = (2 * oh) * 34 + 2 * ow;
  float xv[48];  // 3 ci x 4 rows x 4 cols
  #pragma unroll
  for (int ci = 0; ci < 3; ++ci)
    #pragma unroll
    for (int dr = 0; dr < 4; ++dr)
      #pragma unroll
      for (int dx = 0; dx < 4; ++dx)
        xv[ci * 16 + dr * 4 + dx] = xt[ci * 1156 + wbase + dr * 34 + dx];

  const float pw0 = pw[0] * 10.f, pw1 = pw[1] * 10.f;
  const float pb0 = pb[0] * 10.f, pb1 = pb[1] * 10.f;
  #pragma unroll
  for (int cl = 0; cl < 8; ++cl) {
    const int c = c0 + cl;
    const float scale = stats1[c], shift = stats1[16 + c];
    float v[4];
    #pragma unroll
    for (int p = 0; p < 4; ++p) {
      int dh = p >> 1, dw = p & 1;
      float a = b1[c];
      #pragma unroll
      for (int ci = 0; ci < 3; ++ci)
        #pragma unroll
        for (int ky = 0; ky < 3; ++ky)
          #pragma unroll
          for (int kx = 0; kx < 3; ++kx)
            a = fmaf(xv[ci * 16 + (dh + ky) * 4 + (dw + kx)], w1[(c * 3 + ci) * 9 + ky * 3 + kx], a);
      a = fmaf(a, scale, shift);
      v[p] = fmaxf(a, 0.f);
    }
    #pragma unroll
    for (int k = 0; k < 2; ++k) {
      float cw = k ? pw1 : pw0;
      float cb = k ? pb1 : pb0;
      float s0 = fmaf(v[0], cw, cb), s1 = fmaf(v[1], cw, cb);
      float s2 = fmaf(v[2], cw, cb), s3 = fmaf(v[3], cw, cb);
      float m = fmaxf(fmaxf(s0, s1), fmaxf(s2, s3));
      float e0 = expf(s0 - m), e1 = expf(s1 - m), e2 = expf(s2 - m), e3 = expf(s3 - m);
      float den = e0 + e1 + e2 + e3;
      float outv = (v[0] * e0 + v[1] * e1 + v[2] * e2 + v[3] * e3) / den;
      h1[((b * 32 + (c * 2 + k)) * 16 + oh) * 16 + ow] = outv;
    }
  }
}

// K4 v7: conv2, no LDS, grid (1024, 2). Block g covers co g*16..g*16+15;
// wave w owns co quad co0 = g*16 + w*4 (wave-uniform -> scalar weights, 36/ci).
// Lane: col c = s&15, rows r0..r0+3. Fused BN2 partial stats.
__global__ __launch_bounds__(256) void k4_conv2(
    const float* __restrict__ h1, const float* __restrict__ w2, const float* __restrict__ b2,
    float* __restrict__ y2, float* __restrict__ partials) {
  const int tid = threadIdx.x, b = blockIdx.x;
  const int s = tid & 63;
  const int co0 = blockIdx.y * 16 + (tid >> 6) * 4;   // wave-uniform
  const int c = s & 15, r0 = (s >> 4) * 4;

  int voff[18];
  float vmul[18];
  #pragma unroll
  for (int dr = 0; dr < 6; ++dr) {
    int ir = r0 - 1 + dr;
    int rc = min(max(ir, 0), 15);
    bool rok = ((unsigned)ir < 16u);
    #pragma unroll
    for (int dx = 0; dx < 3; ++dx) {
      int ic = c - 1 + dx;
      int cc = min(max(ic, 0), 15);
      voff[dr * 3 + dx] = rc * 16 + cc;
      vmul[dr * 3 + dx] = (rok && ((unsigned)ic < 16u)) ? 1.f : 0.f;
    }
  }

  const float* hb = h1 + b * 8192;
  float acc[16];  // [j=co][p=row]
  #pragma unroll
  for (int j = 0; j < 4; ++j) {
    float bj = b2[co0 + j];
    #pragma unroll
    for (int p = 0; p < 4; ++p) acc[j * 4 + p] = bj;
  }

  #pragma unroll 2
  for (int ci = 0; ci < 32; ++ci) {
    const float* p = hb + ci * 256;
    float xv[18];
    #pragma unroll
    for (int j = 0; j < 18; ++j) xv[j] = p[voff[j]] * vmul[j];
    const float* wp = w2 + (co0 * 32 + ci) * 9;  // wave-uniform -> scalar loads
    #pragma unroll
    for (int j = 0; j < 4; ++j) {
      #pragma unroll
      for (int ky = 0; ky < 3; ++ky) {
        #pragma unroll
        for (int kx = 0; kx < 3; ++kx) {
          float w = wp[j * 288 + ky * 3 + kx];
          #pragma unroll
          for (int pp = 0; pp < 4; ++pp)
            acc[j * 4 + pp] = fmaf(xv[(pp + ky) * 3 + kx], w, acc[j * 4 + pp]);
        }
      }
    }
  }

  // Write y2 for this wave's co-quad.
  {
    float* yb = y2 + b * 8192 + co0 * 256;
    #pragma unroll
    for (int j = 0; j < 4; ++j)
      #pragma unroll
      for (int p = 0; p < 4; ++p)
        yb[j * 256 + (r0 + p) * 16 + c] = acc[j * 4 + p];
  }

  // Fused BN2 partial stats (in-wave shuffle reduce).
  const int lane = tid & 63;
  #pragma unroll
  for (int j = 0; j < 4; ++j) {
    float a0 = acc[j * 4], a1 = acc[j * 4 + 1], a2 = acc[j * 4 + 2], a3 = acc[j * 4 + 3];
    float sum = a0 + a1 + a2 + a3;
    float sq  = fmaf(a0, a0, fmaf(a1, a1, fmaf(a2, a2, a3 * a3)));
    #pragma unroll
    for (int o = 32; o > 0; o >>= 1) {
      sum += __shfl_down(sum, o, 64);
      sq  += __shfl_down(sq, o, 64);
    }
    if (lane == 0) {
      partials[((co0 + j) * 2 + 0) * 1024 + b] = sum;
      partials[((co0 + j) * 2 + 1) * 1024 + b] = sq;
    }
  }
}

// K78: fused BN2-finalized pool2 + FC. One block per image.
__global__ __launch_bounds__(256) void k78_pool2_fc(
    const float* __restrict__ y2, const float* __restrict__ stats2,
    const float* __restrict__ pw, const float* __restrict__ pb,
    const float* __restrict__ fcw, const float* __restrict__ fcb,
    float* __restrict__ out) {
  __shared__ float h2s[4096];
  __shared__ float red[40];
  const int tid = threadIdx.x;
  const int b = blockIdx.x;

  {
    const int c = tid >> 3, oh = tid & 7;
    const float scale = stats2[c], shift = stats2[32 + c];
    const float pw0 = pw[0] * 10.f, pw1 = pw[1] * 10.f;
    const float pb0 = pb[0] * 10.f, pb1 = pb[1] * 10.f;
    const float* yb = y2 + (b * 32 + c) * 256 + (2 * oh) * 16;
    float rowa[16], rowb[16];
    #pragma unroll
    for (int k = 0; k < 4; ++k) {
      *(float4*)&rowa[k * 4] = ((const float4*)yb)[k];
      *(float4*)&rowb[k * 4] = ((const float4*)(yb + 16))[k];
    }
    #pragma unroll
    for (int ow = 0; ow < 8; ++ow) {
      float v0 = fmaxf(fmaf(rowa[2 * ow],     scale, shift), 0.f);
      float v1 = fmaxf(fmaf(rowa[2 * ow + 1], scale, shift), 0.f);
      float v2 = fmaxf(fmaf(rowb[2 * ow],     scale, shift), 0.f);
      float v3 = fmaxf(fmaf(rowb[2 * ow + 1], scale, shift), 0.f);
      #pragma unroll
      for (int k = 0; k < 2; ++k) {
        float cw = k ? pw1 : pw0;
        float cb = k ? pb1 : pb0;
        float s0 = fmaf(v0, cw, cb), s1 = fmaf(v1, cw, cb);
        float s2 = fmaf(v2, cw, cb), s3 = fmaf(v3, cw, cb);
        float m = fmaxf(fmaxf(s0, s1), fmaxf(s2, s3));
        float e0 = expf(s0 - m), e1 = expf(s1 - m), e2 = expf(s2 - m), e3 = expf(s3 - m);
        float den = e0 + e1 + e2 + e3;
        h2s[(c * 2 + k) * 64 + oh * 8 + ow] =
            (v0 * e0 + v1 * e1 + v2 * e2 + v3 * e3) / den;
      }
    }
  }
  __syncthreads();

  float acc[10];
  #pragma unroll
  for (int j = 0; j < 10; ++j) acc[j] = 0.f;
  #pragma unroll
  for (int k = 0; k < 16; ++k) {
    float hv = h2s[k * 256 + tid];
    #pragma unroll
    for (int j = 0; j < 10; ++j)
      acc[j] = fmaf(hv, fcw[j * 4096 + k * 256 + tid], acc[j]);
  }
  const int lane = tid & 63, wid = tid >> 6;
  #pragma unroll
  for (int j = 0; j < 10; ++j) {
    float v = acc[j];
    #pragma unroll
    for (int off = 32; off > 0; off >>= 1) v += __shfl_down(v, off, 64);
    if (lane == 0) red[wid * 10 + j] = v;
  }
  __syncthreads();
  if (tid < 10) {
    out[b * 10 + tid] = red[tid] + red[10 + tid] + red[20 + tid] + red[30 + tid] + fcb[tid];
  }
}

extern "C" void kernel_launch(void* const* d_in, const int* in_sizes, int n_in,
                              void* d_out, int out_size, void* d_ws, size_t ws_size,
                              hipStream_t stream) {
  (void)in_sizes; (void)n_in; (void)out_size; (void)ws_size;
  const float* x   = (const float*)d_in[0];
  const float* w1  = (const float*)d_in[1];
  const float* b1  = (const float*)d_in[2];
  const float* g1  = (const float*)d_in[3];
  const float* be1 = (const float*)d_in[4];
  const float* pw1 = (const float*)d_in[5];
  const float* pb1 = (const float*)d_in[6];
  const float* w2  = (const float*)d_in[7];
  const float* b2  = (const float*)d_in[8];
  const float* g2  = (const float*)d_in[9];
  const float* be2 = (const float*)d_in[10];
  const float* pw2 = (const float*)d_in[11];
  const float* pb2 = (const float*)d_in[12];
  const float* fcw = (const float*)d_in[13];
  const float* fcb = (const float*)d_in[14];
  float* out = (float*)d_out;

  char* ws = (char*)d_ws;
  float* h1       = (float*)(ws);                         // 32 MiB
  float* y2       = (float*)(ws + 33554432);              // 32 MiB
  float* partials = (float*)(ws + 67108864);              // 256 KiB
  float* stats1   = (float*)(ws + 67108864 + 262144);     // 32 floats
  float* stats2   = stats1 + 32;                          // 64 floats

  dim3 g2d(1024, 2);
  k1_conv1_stats<<<g2d, 256, 0, stream>>>(x, w1, b1, partials);
  k_bn_finalize<<<16, 256, 0, stream>>>(partials, 1024, 1.f / 1048576.f, g1, be1, stats1, 16);
  k3_pool1<<<g2d, 256, 0, stream>>>(x, w1, b1, stats1, pw1, pb1, h1);
  k4_conv2<<<g2d, 256, 0, stream>>>(h1, w2, b2, y2, partials);
  k_bn_finalize<<<32, 256, 0, stream>>>(partials, 1024, 1.f / 262144.f, g2, be2, stats2, 32);
  k78_pool2_fc<<<1024, 256, 0, stream>>>(y2, stats2, pw2, pb2, fcw, fcb, out);
}

// Round 9
// 154.783 us; speedup vs baseline: 1.4878x; 1.4878x over previous
//
#include <hip/hip_runtime.h>

#define EPSV 1e-5f

__device__ __forceinline__ float block_reduce_sum(float v, float* lds) {
  #pragma unroll
  for (int off = 32; off > 0; off >>= 1) v += __shfl_down(v, off, 64);
  int lane = threadIdx.x & 63;
  int wid  = threadIdx.x >> 6;
  __syncthreads();
  if (lane == 0) lds[wid] = v;
  __syncthreads();
  float r = 0.f;
  if (threadIdx.x == 0) {
    int nw = blockDim.x >> 6;
    for (int i = 0; i < nw; ++i) r += lds[i];
  }
  return r;
}

// Stage x[b] (3x32x32) into zero-padded LDS [3][34][34].
__device__ __forceinline__ void stage_x(const float* __restrict__ x, float* xt, int b, int tid) {
  {
    float4* t4 = (float4*)xt;
    #pragma unroll
    for (int i = 0; i < 4; ++i) {
      int idx = i * 256 + tid;
      if (idx < 867) t4[idx] = make_float4(0.f, 0.f, 0.f, 0.f);
    }
  }
  __syncthreads();
  {
    const float4* x4 = (const float4*)(x + b * 3072);
    #pragma unroll
    for (int k = 0; k < 3; ++k) {
      int e4 = k * 256 + tid;
      float4 v = x4[e4];
      int w0 = e4 * 4;
      int ch = w0 >> 10;
      int pos = w0 & 1023;
      int r = pos >> 5, c = pos & 31;
      int base = ch * 1156 + (r + 1) * 34 + (c + 1);
      xt[base] = v.x; xt[base + 1] = v.y; xt[base + 2] = v.z; xt[base + 3] = v.w;
    }
  }
  __syncthreads();
}

// K1 v4: conv1 + stats partials; grid (1024, 2). Block (0,*) also transposes
// w2 -> wt[ci][co][9] for k4's scalar weight stream.
__global__ __launch_bounds__(256) void k1_conv1_stats(
    const float* __restrict__ x, const float* __restrict__ w1, const float* __restrict__ b1,
    float* __restrict__ partials /* [16][2][1024] */,
    const float* __restrict__ w2, float* __restrict__ wt) {
  __shared__ float xt[3468];
  __shared__ float red[64];
  const int tid = threadIdx.x, b = blockIdx.x;
  const int co0 = blockIdx.y * 8;

  if (b == 0) {  // one-time weight transpose (stream-ordered before k4)
    int base = blockIdx.y * 4608;
    for (int i = tid; i < 4608; i += 256) {
      int t = base + i;
      int co = t / 288;
      int rem = t - co * 288;
      int ci = rem / 9;
      int k = rem - ci * 9;
      wt[ci * 288 + co * 9 + k] = w2[t];
    }
  }

  stage_x(x, xt, b, tid);

  const int c = tid & 31, r0 = (tid >> 5) * 4;
  const int sbase = r0 * 34 + c;
  float xv[54];  // 3 ci x 6 rows x 3 cols
  #pragma unroll
  for (int ci = 0; ci < 3; ++ci)
    #pragma unroll
    for (int dr = 0; dr < 6; ++dr)
      #pragma unroll
      for (int dx = 0; dx < 3; ++dx)
        xv[ci * 18 + dr * 3 + dx] = xt[ci * 1156 + sbase + dr * 34 + dx];

  const int lane = tid & 63, wid = tid >> 6;
  #pragma unroll
  for (int cl = 0; cl < 8; ++cl) {
    const int co = co0 + cl;
    float a0, a1, a2, a3;
    a0 = a1 = a2 = a3 = b1[co];
    #pragma unroll
    for (int ci = 0; ci < 3; ++ci)
      #pragma unroll
      for (int ky = 0; ky < 3; ++ky)
        #pragma unroll
        for (int kx = 0; kx < 3; ++kx) {
          float w = w1[co * 27 + ci * 9 + ky * 3 + kx];
          a0 = fmaf(xv[ci * 18 + (0 + ky) * 3 + kx], w, a0);
          a1 = fmaf(xv[ci * 18 + (1 + ky) * 3 + kx], w, a1);
          a2 = fmaf(xv[ci * 18 + (2 + ky) * 3 + kx], w, a2);
          a3 = fmaf(xv[ci * 18 + (3 + ky) * 3 + kx], w, a3);
        }
    float s = a0 + a1 + a2 + a3;
    float q = fmaf(a0, a0, fmaf(a1, a1, fmaf(a2, a2, a3 * a3)));
    #pragma unroll
    for (int o = 32; o > 0; o >>= 1) {
      s += __shfl_down(s, o, 64);
      q += __shfl_down(q, o, 64);
    }
    if (lane == 0) { red[wid * 16 + cl * 2] = s; red[wid * 16 + cl * 2 + 1] = q; }
  }
  __syncthreads();
  if (tid < 16) {
    int cl = tid >> 1, sel = tid & 1;
    float r = red[cl * 2 + sel] + red[16 + cl * 2 + sel] +
              red[32 + cl * 2 + sel] + red[48 + cl * 2 + sel];
    partials[((co0 + cl) * 2 + sel) * 1024 + b] = r;
  }
}

// K2/K6: reduce partials -> scale/shift per channel.
__global__ __launch_bounds__(256) void k_bn_finalize(
    const float* __restrict__ partials, int nb, float invN,
    const float* __restrict__ gamma, const float* __restrict__ beta,
    float* __restrict__ stats, int C) {
  __shared__ float lds[4];
  int c = blockIdx.x;
  float s = 0.f, q = 0.f;
  for (int i = threadIdx.x; i < nb; i += blockDim.x) {
    s += partials[(c * 2 + 0) * nb + i];
    q += partials[(c * 2 + 1) * nb + i];
  }
  s = block_reduce_sum(s, lds);
  q = block_reduce_sum(q, lds);
  if (threadIdx.x == 0) {
    float mean = s * invN;
    float var  = q * invN - mean * mean;
    float scale = gamma[c] * rsqrtf(var + EPSV);
    stats[c]     = scale;
    stats[C + c] = beta[c] - mean * scale;
  }
}

// K3 v4: conv1 + BN + ReLU + basis_pool -> h1 PADDED [1024][32][18][18].
// grid (1024, 2): 8 of 16 conv channels (16 of 32 h1 channels). Also zeros
// its channels' borders (disjoint from interior writes, no sync needed).
__global__ __launch_bounds__(256) void k3_pool1(
    const float* __restrict__ x, const float* __restrict__ w1, const float* __restrict__ b1,
    const float* __restrict__ stats1, const float* __restrict__ pw, const float* __restrict__ pb,
    float* __restrict__ h1p) {
  __shared__ float xt[3468];
  const int tid = threadIdx.x, b = blockIdx.x;
  const int c0 = blockIdx.y * 8;

  // Zero borders of this block's 16 h1 channels.
  {
    float* hb = h1p + (b * 32 + c0 * 2) * 324;
    for (int idx = tid; idx < 16 * 324; idx += 256) {
      int chl = idx / 324;
      int pos = idx - chl * 324;
      int r = pos / 18, cc = pos - r * 18;
      if (r == 0 || r == 17 || cc == 0 || cc == 17) hb[chl * 324 + pos] = 0.f;
    }
  }

  stage_x(x, xt, b, tid);

  const int ow = tid & 15, oh = tid >> 4;
  const int wbase = (2 * oh) * 34 + 2 * ow;
  float xv[48];  // 3 ci x 4 rows x 4 cols
  #pragma unroll
  for (int ci = 0; ci < 3; ++ci)
    #pragma unroll
    for (int dr = 0; dr < 4; ++dr)
      #pragma unroll
      for (int dx = 0; dx < 4; ++dx)
        xv[ci * 16 + dr * 4 + dx] = xt[ci * 1156 + wbase + dr * 34 + dx];

  const float pw0 = pw[0] * 10.f, pw1 = pw[1] * 10.f;
  const float pb0 = pb[0] * 10.f, pb1 = pb[1] * 10.f;
  #pragma unroll
  for (int cl = 0; cl < 8; ++cl) {
    const int c = c0 + cl;
    const float scale = stats1[c], shift = stats1[16 + c];
    float v[4];
    #pragma unroll
    for (int p = 0; p < 4; ++p) {
      int dh = p >> 1, dw = p & 1;
      float a = b1[c];
      #pragma unroll
      for (int ci = 0; ci < 3; ++ci)
        #pragma unroll
        for (int ky = 0; ky < 3; ++ky)
          #pragma unroll
          for (int kx = 0; kx < 3; ++kx)
            a = fmaf(xv[ci * 16 + (dh + ky) * 4 + (dw + kx)], w1[(c * 3 + ci) * 9 + ky * 3 + kx], a);
      a = fmaf(a, scale, shift);
      v[p] = fmaxf(a, 0.f);
    }
    #pragma unroll
    for (int k = 0; k < 2; ++k) {
      float cw = k ? pw1 : pw0;
      float cb = k ? pb1 : pb0;
      float s0 = fmaf(v[0], cw, cb), s1 = fmaf(v[1], cw, cb);
      float s2 = fmaf(v[2], cw, cb), s3 = fmaf(v[3], cw, cb);
      float m = fmaxf(fmaxf(s0, s1), fmaxf(s2, s3));
      float e0 = expf(s0 - m), e1 = expf(s1 - m), e2 = expf(s2 - m), e3 = expf(s3 - m);
      float den = e0 + e1 + e2 + e3;
      float outv = (v[0] * e0 + v[1] * e1 + v[2] * e2 + v[3] * e3) / den;
      h1p[(b * 32 + (c * 2 + k)) * 324 + (oh + 1) * 18 + (ow + 1)] = outv;
    }
  }
}

// K4 v8: conv2 from padded h1, no bounds logic. grid(2048): bid = b*2 + half
// (half = rows 0-7 or 8-15). Wave w -> co w*8..w*8+7 (readfirstlane-forced
// SGPR -> scalar weight loads from wt[ci][co][9]). Lane: col c = s&15,
// output rows r2, r2+1 (r2 = (s>>4)*2 + half*8). 12 loads : 144 FMA per ci.
__global__ __launch_bounds__(256, 6) void k4_conv2(
    const float* __restrict__ h1p, const float* __restrict__ wt, const float* __restrict__ b2,
    float* __restrict__ y2, float* __restrict__ partials) {
  const int tid = threadIdx.x;
  const int bid = blockIdx.x;
  const int b = bid >> 1;
  const int half = bid & 1;
  const int s = tid & 63;
  const int co0 = __builtin_amdgcn_readfirstlane(tid >> 6) * 8;  // SGPR
  const int c = s & 15;
  const int r2 = (s >> 4) * 2 + half * 8;   // output rows r2, r2+1

  const float* hb = h1p + b * 10368;        // 32*324
  float acc[16];                            // [j=co][p=row(2)]
  #pragma unroll
  for (int j = 0; j < 8; ++j) {
    float bj = b2[co0 + j];
    acc[j * 2] = bj; acc[j * 2 + 1] = bj;
  }

  #pragma unroll 2
  for (int ci = 0; ci < 32; ++ci) {
    const float* p = hb + ci * 324 + r2 * 18 + c;  // padded window origin
    float xv[12];  // 4 rows x 3 cols
    #pragma unroll
    for (int dr = 0; dr < 4; ++dr) {
      xv[dr * 3 + 0] = p[dr * 18 + 0];
      xv[dr * 3 + 1] = p[dr * 18 + 1];
      xv[dr * 3 + 2] = p[dr * 18 + 2];
    }
    const float* wp = wt + (ci * 32 + co0) * 9;  // SGPR-uniform -> s_load
    #pragma unroll
    for (int j = 0; j < 8; ++j) {
      #pragma unroll
      for (int ky = 0; ky < 3; ++ky) {
        #pragma unroll
        for (int kx = 0; kx < 3; ++kx) {
          float w = wp[j * 9 + ky * 3 + kx];
          acc[j * 2]     = fmaf(xv[(0 + ky) * 3 + kx], w, acc[j * 2]);
          acc[j * 2 + 1] = fmaf(xv[(1 + ky) * 3 + kx], w, acc[j * 2 + 1]);
        }
      }
    }
  }

  // Write y2 (compact) for this wave's co-group, 2 rows.
  {
    float* yb = y2 + b * 8192 + co0 * 256;
    #pragma unroll
    for (int j = 0; j < 8; ++j) {
      yb[j * 256 + r2 * 16 + c]       = acc[j * 2];
      yb[j * 256 + (r2 + 1) * 16 + c] = acc[j * 2 + 1];
    }
  }

  // Fused BN2 partial stats -> partials [32][2][2048].
  const int lane = tid & 63;
  #pragma unroll
  for (int j = 0; j < 8; ++j) {
    float a0 = acc[j * 2], a1 = acc[j * 2 + 1];
    float sum = a0 + a1;
    float sq  = fmaf(a0, a0, a1 * a1);
    #pragma unroll
    for (int o = 32; o > 0; o >>= 1) {
      sum += __shfl_down(sum, o, 64);
      sq  += __shfl_down(sq, o, 64);
    }
    if (lane == 0) {
      partials[((co0 + j) * 2 + 0) * 2048 + bid] = sum;
      partials[((co0 + j) * 2 + 1) * 2048 + bid] = sq;
    }
  }
}

// K78: fused BN2-finalized pool2 + FC. One block per image.
__global__ __launch_bounds__(256) void k78_pool2_fc(
    const float* __restrict__ y2, const float* __restrict__ stats2,
    const float* __restrict__ pw, const float* __restrict__ pb,
    const float* __restrict__ fcw, const float* __restrict__ fcb,
    float* __restrict__ out) {
  __shared__ float h2s[4096];
  __shared__ float red[40];
  const int tid = threadIdx.x;
  const int b = blockIdx.x;

  {
    const int c = tid >> 3, oh = tid & 7;
    const float scale = stats2[c], shift = stats2[32 + c];
    const float pw0 = pw[0] * 10.f, pw1 = pw[1] * 10.f;
    const float pb0 = pb[0] * 10.f, pb1 = pb[1] * 10.f;
    const float* yb = y2 + (b * 32 + c) * 256 + (2 * oh) * 16;
    float rowa[16], rowb[16];
    #pragma unroll
    for (int k = 0; k < 4; ++k) {
      *(float4*)&rowa[k * 4] = ((const float4*)yb)[k];
      *(float4*)&rowb[k * 4] = ((const float4*)(yb + 16))[k];
    }
    #pragma unroll
    for (int ow = 0; ow < 8; ++ow) {
      float v0 = fmaxf(fmaf(rowa[2 * ow],     scale, shift), 0.f);
      float v1 = fmaxf(fmaf(rowa[2 * ow + 1], scale, shift), 0.f);
      float v2 = fmaxf(fmaf(rowb[2 * ow],     scale, shift), 0.f);
      float v3 = fmaxf(fmaf(rowb[2 * ow + 1], scale, shift), 0.f);
      #pragma unroll
      for (int k = 0; k < 2; ++k) {
        float cw = k ? pw1 : pw0;
        float cb = k ? pb1 : pb0;
        float s0 = fmaf(v0, cw, cb), s1 = fmaf(v1, cw, cb);
        float s2 = fmaf(v2, cw, cb), s3 = fmaf(v3, cw, cb);
        float m = fmaxf(fmaxf(s0, s1), fmaxf(s2, s3));
        float e0 = expf(s0 - m), e1 = expf(s1 - m), e2 = expf(s2 - m), e3 = expf(s3 - m);
        float den = e0 + e1 + e2 + e3;
        h2s[(c * 2 + k) * 64 + oh * 8 + ow] =
            (v0 * e0 + v1 * e1 + v2 * e2 + v3 * e3) / den;
      }
    }
  }
  __syncthreads();

  float acc[10];
  #pragma unroll
  for (int j = 0; j < 10; ++j) acc[j] = 0.f;
  #pragma unroll
  for (int k = 0; k < 16; ++k) {
    float hv = h2s[k * 256 + tid];
    #pragma unroll
    for (int j = 0; j < 10; ++j)
      acc[j] = fmaf(hv, fcw[j * 4096 + k * 256 + tid], acc[j]);
  }
  const int lane = tid & 63, wid = tid >> 6;
  #pragma unroll
  for (int j = 0; j < 10; ++j) {
    float v = acc[j];
    #pragma unroll
    for (int off = 32; off > 0; off >>= 1) v += __shfl_down(v, off, 64);
    if (lane == 0) red[wid * 10 + j] = v;
  }
  __syncthreads();
  if (tid < 10) {
    out[b * 10 + tid] = red[tid] + red[10 + tid] + red[20 + tid] + red[30 + tid] + fcb[tid];
  }
}

extern "C" void kernel_launch(void* const* d_in, const int* in_sizes, int n_in,
                              void* d_out, int out_size, void* d_ws, size_t ws_size,
                              hipStream_t stream) {
  (void)in_sizes; (void)n_in; (void)out_size; (void)ws_size;
  const float* x   = (const float*)d_in[0];
  const float* w1  = (const float*)d_in[1];
  const float* b1  = (const float*)d_in[2];
  const float* g1  = (const float*)d_in[3];
  const float* be1 = (const float*)d_in[4];
  const float* pw1 = (const float*)d_in[5];
  const float* pb1 = (const float*)d_in[6];
  const float* w2  = (const float*)d_in[7];
  const float* b2  = (const float*)d_in[8];
  const float* g2  = (const float*)d_in[9];
  const float* be2 = (const float*)d_in[10];
  const float* pw2 = (const float*)d_in[11];
  const float* pb2 = (const float*)d_in[12];
  const float* fcw = (const float*)d_in[13];
  const float* fcb = (const float*)d_in[14];
  float* out = (float*)d_out;

  char* ws = (char*)d_ws;
  float* h1p      = (float*)(ws);                          // 1024*32*324*4 = 42.47 MB
  float* y2       = (float*)(ws + 44040192);               // 32 MiB
  float* partials = (float*)(ws + 44040192 + 33554432);    // 512 KiB ([32][2][2048])
  float* wt       = (float*)(ws + 44040192 + 33554432 + 524288);  // 36 KiB
  float* stats1   = (float*)(ws + 44040192 + 33554432 + 524288 + 36864);
  float* stats2   = stats1 + 32;

  dim3 g2d(1024, 2);
  k1_conv1_stats<<<g2d, 256, 0, stream>>>(x, w1, b1, partials, w2, wt);
  k_bn_finalize<<<16, 256, 0, stream>>>(partials, 1024, 1.f / 1048576.f, g1, be1, stats1, 16);
  k3_pool1<<<g2d, 256, 0, stream>>>(x, w1, b1, stats1, pw1, pb1, h1p);
  k4_conv2<<<2048, 256, 0, stream>>>(h1p, wt, b2, y2, partials);
  k_bn_finalize<<<32, 256, 0, stream>>>(partials, 2048, 1.f / 262144.f, g2, be2, stats2, 32);
  k78_pool2_fc<<<1024, 256, 0, stream>>>(y2, stats2, pw2, pb2, fcw, fcb, out);
}